// Round 1
// baseline (117.095 us; speedup 1.0000x reference)
//
#include <hip/hip_runtime.h>
#include <stdint.h>

typedef unsigned int u32;
typedef unsigned short u16;
typedef unsigned long long u64;

#define NB 512                      // histogram bins over error in [0,1]
#define NC 20                       // classes
#define K1_BLOCK 256
#define HIST_U32 (NC * NB * 2)      // 20480 counters: tot[20][512] then fg[20][512]
#define DUMP_BYTES (HIST_U32 * 2)   // u16 dump per block = 40960 B
#define OFF_CE   (HIST_U32 * 4)     // final hist is u32 at ws[0..81920)
#define OFF_CNT  (OFF_CE + 4)
#define OFF_DUMPS 98304             // 96 KiB reserved (final hist + accums)
#define RESERVED  OFF_DUMPS

// ---------------- kernel 1: softmax + CE + privatized histograms ----------------
__global__ __launch_bounds__(K1_BLOCK) void k1_hist(
    const float* __restrict__ logits, const int* __restrict__ tgt, int P,
    u16* __restrict__ dumps, float* __restrict__ ce_sum, u32* __restrict__ valid_cnt)
{
    __shared__ u32 lds[HIST_U32];           // 80 KiB
    __shared__ float ce_w[4];
    __shared__ u32   cnt_w[4];

    for (int i = threadIdx.x; i < HIST_U32; i += K1_BLOCK) lds[i] = 0;
    __syncthreads();

    float ce_part = 0.f;
    u32   cnt_part = 0;

    for (long long idx = (long long)blockIdx.x * K1_BLOCK + threadIdx.x; idx < P;
         idx += (long long)gridDim.x * K1_BLOCK) {
        const float* row = logits + idx * NC;
        float4 v0 = *(const float4*)(row + 0);
        float4 v1 = *(const float4*)(row + 4);
        float4 v2 = *(const float4*)(row + 8);
        float4 v3 = *(const float4*)(row + 12);
        float4 v4 = *(const float4*)(row + 16);
        float x[NC] = { v0.x, v0.y, v0.z, v0.w,  v1.x, v1.y, v1.z, v1.w,
                        v2.x, v2.y, v2.z, v2.w,  v3.x, v3.y, v3.z, v3.w,
                        v4.x, v4.y, v4.z, v4.w };
        int t = tgt[idx];

        float mx = x[0];
        #pragma unroll
        for (int c = 1; c < NC; ++c) mx = fmaxf(mx, x[c]);

        float e[NC];
        float s = 0.f;
        #pragma unroll
        for (int c = 0; c < NC; ++c) { e[c] = __expf(x[c] - mx); s += e[c]; }
        float inv = 1.0f / s;
        float lse = __logf(s);

        float xt = 0.f;
        #pragma unroll
        for (int c = 0; c < NC; ++c) xt = (c == t) ? x[c] : xt;
        if (t != 0) { ce_part += (mx + lse - xt); cnt_part++; }

        #pragma unroll
        for (int c = 0; c < NC; ++c) {
            float p = e[c] * inv;
            float err = (c == t) ? (1.0f - p) : p;
            int b = (int)(err * (float)NB);
            b = b < 0 ? 0 : (b > NB - 1 ? NB - 1 : b);
            atomicAdd(&lds[c * NB + b], 1u);
            if (c == t) atomicAdd(&lds[NC * NB + c * NB + b], 1u);
        }
    }

    // block CE reduction
    #pragma unroll
    for (int off = 32; off > 0; off >>= 1) {
        ce_part  += __shfl_down(ce_part, off);
        cnt_part += __shfl_down(cnt_part, off);
    }
    int lane = threadIdx.x & 63, wid = threadIdx.x >> 6;
    if (lane == 0) { ce_w[wid] = ce_part; cnt_w[wid] = cnt_part; }
    __syncthreads();
    if (threadIdx.x == 0) {
        atomicAdd(ce_sum,  ce_w[0] + ce_w[1] + ce_w[2] + ce_w[3]);
        atomicAdd(valid_cnt, cnt_w[0] + cnt_w[1] + cnt_w[2] + cnt_w[3]);
    }
    __syncthreads();

    // non-atomic per-block dump (u16 is safe: <=~3906 points per block)
    u16* d = dumps + (size_t)blockIdx.x * HIST_U32;
    for (int i = threadIdx.x; i < HIST_U32; i += K1_BLOCK) d[i] = (u16)lds[i];
}

// ---------------- kernel 2a: reduce per-block dumps into final hist ----------------
__global__ __launch_bounds__(256) void k2a_reduce(
    const u16* __restrict__ dumps, u32* __restrict__ final_hist, int nblk, int chunk)
{
    int counter = (blockIdx.x % 80) * 256 + threadIdx.x;   // 80*256 == 20480
    int part    = blockIdx.x / 80;
    int b0 = part * chunk;
    int b1 = b0 + chunk; if (b1 > nblk) b1 = nblk;
    u32 ssum = 0;
    for (int blk = b0; blk < b1; ++blk)
        ssum += dumps[(size_t)blk * HIST_U32 + counter];
    if (ssum) atomicAdd(&final_hist[counter], ssum);
}

// ---------------- kernel 2b: per-class descending bin scan + finalize ----------------
__device__ __forceinline__ float jac_of(float gts, u32 cf, u32 ct)
{
    // jac = 1 - (gts - cumfg) / (gts + cumtot - cumfg); safe when gts > 0 (ct>=cf)
    float I = gts - (float)cf;
    float U = gts + (float)ct - (float)cf;
    return 1.0f - I / U;
}

__global__ __launch_bounds__(256) void k2b_final(
    const u32* __restrict__ final_hist, const float* __restrict__ ce_sum,
    const u32* __restrict__ valid_cnt, float* __restrict__ outp)
{
    __shared__ u64 sc[256];
    __shared__ float red[256];
    int t = threadIdx.x;

    float lovsum = 0.f;
    int prescnt = 0;

    for (int c = 0; c < NC; ++c) {
        // two reversed bins per thread (descending error order)
        int b0 = NB - 1 - (2 * t);
        int b1 = NB - 1 - (2 * t + 1);
        u32 t0 = final_hist[c * NB + b0], f0 = final_hist[NC * NB + c * NB + b0];
        u32 t1 = final_hist[c * NB + b1], f1 = final_hist[NC * NB + c * NB + b1];
        u64 v0 = ((u64)f0 << 32) | (u64)t0;
        u64 v1 = ((u64)f1 << 32) | (u64)t1;
        u64 local = v0 + v1;

        sc[t] = local;
        __syncthreads();
        for (int off = 1; off < 256; off <<= 1) {
            u64 add = (t >= off) ? sc[t - off] : 0ull;
            __syncthreads();
            sc[t] += add;
            __syncthreads();
        }
        u64 incl  = sc[t];
        u64 total = sc[255];
        float gts = (float)(u32)(total >> 32);

        float contrib = 0.f;
        if (gts > 0.f) {
            u64 excl = incl - local;
            u64 i0 = excl + v0;     // inclusive through bin b0
            u64 i1 = i0 + v1;       // inclusive through bin b1
            u32 cfE = (u32)(excl >> 32), ctE = (u32)excl;
            u32 cf0 = (u32)(i0 >> 32),   ct0 = (u32)i0;
            u32 cf1 = (u32)(i1 >> 32),   ct1 = (u32)i1;
            float jE = jac_of(gts, cfE, ctE);
            float j0 = jac_of(gts, cf0, ct0);
            float j1 = jac_of(gts, cf1, ct1);
            float e0 = ((float)b0 + 0.5f) * (1.0f / (float)NB);
            float e1 = ((float)b1 + 0.5f) * (1.0f / (float)NB);
            contrib = e0 * (j0 - jE) + e1 * (j1 - j0);
        }

        red[t] = contrib;
        __syncthreads();
        #pragma unroll
        for (int off = 128; off > 0; off >>= 1) {
            if (t < off) red[t] += red[t + off];
            __syncthreads();
        }
        if (t == 0 && gts > 0.f) { lovsum += red[0]; prescnt++; }
        __syncthreads();
    }

    if (t == 0) {
        u32 vc = *valid_cnt; if (vc < 1u) vc = 1u;
        float ce = *ce_sum / (float)vc;
        int pc = prescnt < 1 ? 1 : prescnt;
        float lov = lovsum / (float)pc;
        outp[0] = 2.0f * ce;
        outp[1] = 6.0f * lov;
    }
}

// ---------------- launch ----------------
extern "C" void kernel_launch(void* const* d_in, const int* in_sizes, int n_in,
                              void* d_out, int out_size, void* d_ws, size_t ws_size,
                              hipStream_t stream)
{
    const float* logits = (const float*)d_in[0];
    const int*   tgt    = (const int*)d_in[1];
    int P = in_sizes[1];

    char* ws = (char*)d_ws;
    u32*  final_hist = (u32*)ws;
    float* ce_sum    = (float*)(ws + OFF_CE);
    u32*  valid_cnt  = (u32*)(ws + OFF_CNT);
    u16*  dumps      = (u16*)(ws + OFF_DUMPS);

    int nblk = 512;
    size_t avail = ws_size > (size_t)RESERVED ? ws_size - RESERVED : 0;
    int maxblk = (int)(avail / DUMP_BYTES);
    if (maxblk < 1) maxblk = 1;
    if (nblk > maxblk) nblk = maxblk;

    hipMemsetAsync(d_ws, 0, RESERVED, stream);
    hipLaunchKernelGGL(k1_hist, dim3(nblk), dim3(K1_BLOCK), 0, stream,
                       logits, tgt, P, dumps, ce_sum, valid_cnt);
    int split = nblk >= 8 ? 8 : 1;
    int chunk = (nblk + split - 1) / split;
    hipLaunchKernelGGL(k2a_reduce, dim3(80 * split), dim3(256), 0, stream,
                       dumps, final_hist, nblk, chunk);
    hipLaunchKernelGGL(k2b_final, dim3(1), dim3(256), 0, stream,
                       final_hist, ce_sum, valid_cnt, (float*)d_out);
}